// Round 2
// 611.743 us; speedup vs baseline: 1.0166x; 1.0166x over previous
//
#include <hip/hip_runtime.h>
#include <stdint.h>

#define NN    50000
#define INC   128
#define HIDC  256
#define OUTC  40
#define GCH   128
#define NL    4
#define NG    2
#define NEDGE 600000
#define EPSV  1e-5f

typedef __bf16 bf16x8 __attribute__((ext_vector_type(8)));
typedef float  f32x4  __attribute__((ext_vector_type(4)));
typedef unsigned short u16x4 __attribute__((ext_vector_type(4)));
typedef unsigned short u16x8 __attribute__((ext_vector_type(8)));

__device__ __forceinline__ float bf2f(unsigned short u) {
    union { float f; unsigned int i; } v;
    v.i = ((unsigned int)u) << 16;
    return v.f;
}
__device__ __forceinline__ unsigned short f2bf(float f) {
    union { float f; unsigned int i; } v;
    v.f = f;
    unsigned int u = v.i;
    u += 0x7FFFu + ((u >> 16) & 1u);   // RNE
    return (unsigned short)(u >> 16);
}
__device__ __forceinline__ float ldf(const void* p, int is_f32, long long i) {
    if (is_f32) return ((const float*)p)[i];
    return bf2f(((const unsigned short*)p)[i]);
}
__device__ __forceinline__ bf16x8 ld8(const unsigned short* p) {
    return *(const bf16x8*)p;
}
// async global->LDS, 16B per lane. LDS dest is linear (wave base + lane*16);
// swizzling is done on the GLOBAL source address (rule: both-sides-or-neither).
__device__ __forceinline__ void gload_lds16(const void* g, void* l) {
    __builtin_amdgcn_global_load_lds(
        (const __attribute__((address_space(1))) unsigned int*)g,
        (__attribute__((address_space(3))) unsigned int*)l,
        16, 0, 0);
}

// ---- diagnostic marker ----
__global__ void k_marker(void* out, float val, int n) {
    int i = blockIdx.x * 256 + threadIdx.x;
    if (i < n) ((unsigned short*)out)[i] = f2bf(val);
}

// ---- zero deg + dhist + detect dtypes ----
__global__ void k_detect(const int* ei, const unsigned short* xprobe,
                         int* flags, int* deg, int* dhist) {
    int t = threadIdx.x;
    int gid = blockIdx.x * 256 + t;
    if (gid < NN) deg[gid] = 0;
    if (gid < 64) dhist[gid] = 0;
    if (blockIdx.x == 0) {
        __shared__ int hi_or;
        __shared__ int wild_cnt;
        if (t == 0) { hi_or = 0; wild_cnt = 0; }
        __syncthreads();
        int acc = 0;
        for (int i = 0; i < 8; i++) acc |= ei[2 * (t + i * 256) + 1];
        if (acc) atomicOr(&hi_or, 1);
        int wild = 0;
        for (int i = 0; i < 2; i++) {
            unsigned short u = xprobe[t + i * 256];
            int e = (u >> 7) & 0xFF;
            if (e <= 0x30 || e >= 0xC0) wild++;
        }
        atomicAdd(&wild_cnt, wild);
        __syncthreads();
        if (t == 0) {
            flags[0] = hi_or ? 0 : 1;           // 1 => int64 edge_index
            flags[1] = (wild_cnt > 32) ? 1 : 0; // 1 => fp32 float tensors
        }
    }
}

// ---- one-time convert (merged: weights + small params) ----
#define CVT_X   6400000
#define CVT_W1  32768
#define CVT_CW  131072
#define CVT_W2  12288
#define CVT_TOT (CVT_X + CVT_W1 + CVT_CW + CVT_W2)

__global__ void k_convert(const void* x, const void* w1, const void* cw, const void* w2,
                          const void* b1, const void* ng, const void* nb, const void* cb,
                          const void* fg, const void* fb, const void* b2,
                          const int* flags,
                          unsigned short* xb, unsigned short* w1t,
                          unsigned short* cwt, unsigned short* w2t,
                          float* b1f, float* ngf, float* nbf, float* cbf,
                          float* fgf, float* fbf, float* b2f) {
    int t = threadIdx.x;
    int f32 = flags[1];
    if (blockIdx.x == gridDim.x - 1) {          // former k_convert2
        b1f[t] = ldf(b1, f32, t);
        fgf[t] = ldf(fg, f32, t);
        fbf[t] = ldf(fb, f32, t);
        if (t < 48) b2f[t] = (t < OUTC) ? ldf(b2, f32, t) : 0.0f;
        for (int i = 0; i < 4; i++) {
            int j = t + i * 256;
            ngf[j] = ldf(ng, f32, j);
            nbf[j] = ldf(nb, f32, j);
            cbf[j] = ldf(cb, f32, j);
        }
        return;
    }
    long long idx = (long long)blockIdx.x * 256 + t;
    if (idx >= CVT_TOT) return;
    if (idx < CVT_X) {
        if (!f32) return;                      // bf16 input: lin1 reads x directly
        xb[idx] = f2bf(ldf(x, 1, idx));
    } else if (idx < CVT_X + CVT_W1) {
        long long j = idx - CVT_X;
        int n = (int)(j >> 7), k = (int)(j & 127);
        w1t[j] = f2bf(ldf(w1, f32, (long long)k * HIDC + n));
    } else if (idx < CVT_X + CVT_W1 + CVT_CW) {
        long long j = idx - (CVT_X + CVT_W1);
        int lg = (int)(j >> 14);
        int rem = (int)(j & 16383);
        int n = rem >> 7, k = rem & 127;
        cwt[j] = f2bf(ldf(cw, f32, (long long)lg * GCH * GCH + (long long)k * GCH + n));
    } else {
        long long j = idx - (CVT_X + CVT_W1 + CVT_CW);
        int n = (int)(j >> 8), k = (int)(j & 255);
        w2t[j] = (n < OUTC) ? f2bf(ldf(w2, f32, (long long)k * OUTC + n)) : (unsigned short)0;
    }
}

// ---- lin1: h = x @ W1 + b1 (h bf16) ----
__global__ __launch_bounds__(256) void k_lin1(
    const unsigned short* __restrict__ x_raw,
    const unsigned short* __restrict__ xb,
    const unsigned short* __restrict__ w1t,
    const float* __restrict__ b1f,
    const int* __restrict__ flags,
    unsigned short* __restrict__ h)
{
    const unsigned short* xs = flags[1] ? xb : x_raw;
    int bx = blockIdx.x;
    int r0 = (bx >> 1) * 128;
    int n0 = (bx & 1) * 128;
    int w = threadIdx.x >> 6, lane = threadIdx.x & 63;
    int quad = lane >> 4, ln = lane & 15;
    const f32x4 zf = {0.f, 0.f, 0.f, 0.f};
    const bf16x8 zb = {0, 0, 0, 0, 0, 0, 0, 0};
    f32x4 acc[2][8];
#pragma unroll
    for (int i = 0; i < 2; i++)
#pragma unroll
        for (int j = 0; j < 8; j++) acc[i][j] = zf;

#pragma unroll
    for (int kk = 0; kk < 4; kk++) {
        int ko = kk * 32 + quad * 8;
        bf16x8 a0, a1;
        {
            int r = r0 + w * 32 + ln;
            a0 = (r < NN) ? ld8(xs + (long long)r * INC + ko) : zb;
            r += 16;
            a1 = (r < NN) ? ld8(xs + (long long)r * INC + ko) : zb;
        }
#pragma unroll
        for (int nf = 0; nf < 8; nf++) {
            bf16x8 b = ld8(w1t + (long long)(n0 + nf * 16 + ln) * INC + ko);
            acc[0][nf] = __builtin_amdgcn_mfma_f32_16x16x32_bf16(a0, b, acc[0][nf], 0, 0, 0);
            acc[1][nf] = __builtin_amdgcn_mfma_f32_16x16x32_bf16(a1, b, acc[1][nf], 0, 0, 0);
        }
    }
#pragma unroll
    for (int mi = 0; mi < 2; mi++)
#pragma unroll
        for (int nf = 0; nf < 8; nf++) {
            int col = n0 + nf * 16 + ln;
            float bias = b1f[col];
#pragma unroll
            for (int r4 = 0; r4 < 4; r4++) {
                int row = r0 + w * 32 + mi * 16 + quad * 4 + r4;
                if (row < NN) h[(long long)row * HIDC + col] = f2bf(acc[mi][nf][r4] + bias);
            }
        }
}

// ---- layer-0 LN+ReLU: amat = relu(LN(h half1)) (once; later blocks fuse into agg) ----
__global__ __launch_bounds__(256) void k_ln_amat(
    const unsigned short* __restrict__ h,
    const float* __restrict__ ga, const float* __restrict__ be,
    unsigned short* __restrict__ amat)
{
    int slot = blockIdx.x * 16 + (threadIdx.x >> 4);
    int c8 = (threadIdx.x & 15) << 3;
    u16x8 v = *(const u16x8*)(h + (long long)slot * HIDC + GCH + c8);
    float y[8]; float sum = 0.f, sq = 0.f;
#pragma unroll
    for (int j = 0; j < 8; j++) { y[j] = bf2f(v[j]); sum += y[j]; sq += y[j] * y[j]; }
    sum += __shfl_xor(sum, 1, 64); sum += __shfl_xor(sum, 2, 64);
    sum += __shfl_xor(sum, 4, 64); sum += __shfl_xor(sum, 8, 64);
    sq  += __shfl_xor(sq, 1, 64);  sq  += __shfl_xor(sq, 2, 64);
    sq  += __shfl_xor(sq, 4, 64);  sq  += __shfl_xor(sq, 8, 64);
    float mu = sum * (1.0f / GCH);
    float var = sq * (1.0f / GCH) - mu * mu;
    float rs = rsqrtf(var + EPSV);
    u16x8 o;
#pragma unroll
    for (int j = 0; j < 8; j++) {
        float val = (y[j] - mu) * rs * ga[c8 + j] + be[c8 + j];
        if (val < 0.f) val = 0.f;
        o[j] = f2bf(val);
    }
    *(u16x8*)(amat + (long long)slot * GCH + c8) = o;
}

// ---- lean GEMM: z = amat @ cw^T; A staged via global_load_lds, XOR-swizzled src ----
__global__ __launch_bounds__(256) void k_gemm(
    const unsigned short* __restrict__ amat,
    const unsigned short* __restrict__ cw,
    unsigned short* __restrict__ z)
{
    __shared__ __align__(16) unsigned short a_tile[128 * 128];
    int t = threadIdx.x;
    int r0 = blockIdx.x * 128;
    const char* gb = (const char*)amat + (long long)r0 * 256;
#pragma unroll
    for (int i = 0; i < 8; i++) {
        int lb = (i * 256 + t) * 16;          // linear LDS byte offset
        int row = lb >> 8;
        int c = lb & 255;                      // 16B-aligned chunk within 256B row
        gload_lds16(gb + (long long)row * 256 + (c ^ ((row & 7) << 4)),
                    (char*)a_tile + lb);
    }
    __syncthreads();

    int w = t >> 6, lane = t & 63;
    int quad = lane >> 4, ln = lane & 15;
    const f32x4 zf = {0.f, 0.f, 0.f, 0.f};
    f32x4 acc[2][8];
#pragma unroll
    for (int i = 0; i < 2; i++)
#pragma unroll
        for (int j = 0; j < 8; j++) acc[i][j] = zf;

#pragma unroll
    for (int kk = 0; kk < 4; kk++) {
        int kb = kk * 64 + quad * 16;          // byte offset of K-chunk
        int ko = kk * 32 + quad * 8;           // element offset for B
        int rA = w * 32 + ln;
        int rB = rA + 16;
        bf16x8 a0 = *(const bf16x8*)((const char*)a_tile + rA * 256 + (kb ^ ((rA & 7) << 4)));
        bf16x8 a1 = *(const bf16x8*)((const char*)a_tile + rB * 256 + (kb ^ ((rB & 7) << 4)));
#pragma unroll
        for (int nf = 0; nf < 8; nf++) {
            bf16x8 b = ld8(cw + (long long)(nf * 16 + ln) * GCH + ko);
            acc[0][nf] = __builtin_amdgcn_mfma_f32_16x16x32_bf16(a0, b, acc[0][nf], 0, 0, 0);
            acc[1][nf] = __builtin_amdgcn_mfma_f32_16x16x32_bf16(a1, b, acc[1][nf], 0, 0, 0);
        }
    }
#pragma unroll
    for (int mi = 0; mi < 2; mi++)
#pragma unroll
        for (int nf = 0; nf < 8; nf++) {
            int col = nf * 16 + ln;
#pragma unroll
            for (int r4 = 0; r4 < 4; r4++) {
                int row2 = r0 + w * 32 + mi * 16 + quad * 4 + r4;
                if (row2 < NN) z[(long long)row2 * GCH + col] = f2bf(acc[mi][nf][r4]);
            }
        }
}

// ---- CSR build ----
__global__ void k_count(const int* __restrict__ ei, const int* __restrict__ flags,
                        int* __restrict__ deg) {
    int e = (blockIdx.x * 256 + threadIdx.x) * 2;
    if (e >= NEDGE) return;
    int d0, d1;
    if (flags[0]) {
        int4 v = *(const int4*)(ei + 2 * (NEDGE + e));
        d0 = v.x; d1 = v.z;
    } else {
        int2 v = *(const int2*)(ei + NEDGE + e);
        d0 = v.x; d1 = v.y;
    }
    atomicAdd(&deg[d0], 1);
    if (e + 1 < NEDGE) atomicAdd(&deg[d1], 1);
}

#define SCAN_B 49
__global__ void k_scan_a(const int* __restrict__ deg, int* __restrict__ bsum,
                         int* __restrict__ dhist) {
    __shared__ int part[256];
    __shared__ int lh[64];
    int b = blockIdx.x, t = threadIdx.x;
    if (t < 64) lh[t] = 0;
    __syncthreads();
    int base = b * 1024 + t * 4;
    int s = 0;
#pragma unroll
    for (int j = 0; j < 4; j++) {
        int i = base + j;
        if (i < NN) {
            int d = deg[i];
            s += d;
            atomicAdd(&lh[d > 63 ? 63 : d], 1);
        }
    }
    part[t] = s;
    __syncthreads();
    for (int off = 128; off > 0; off >>= 1) {
        if (t < off) part[t] += part[t + off];
        __syncthreads();
    }
    if (t == 0) bsum[b] = part[0];
    if (t < 64 && lh[t]) atomicAdd(&dhist[t], lh[t]);
}

__global__ void k_scan_c(const int* __restrict__ deg, const int* __restrict__ bsum,
                         int* __restrict__ rowptr, int* __restrict__ cursor,
                         const int* __restrict__ dhist, int* __restrict__ dcur) {
    __shared__ int part[256];
    __shared__ int bbase;
    int b = blockIdx.x, t = threadIdx.x;
    if (t == 0) { int r = 0; for (int i = 0; i < b; i++) r += bsum[i]; bbase = r; }
    if (b == 0 && t == 255) {                // exclusive scan of degree histogram
        int r = 0;
        for (int i = 0; i < 64; i++) { dcur[i] = r; r += dhist[i]; }
    }
    int base = b * 1024 + t * 4;
    int v[4];
    int s = 0;
#pragma unroll
    for (int j = 0; j < 4; j++) {
        int i = base + j;
        v[j] = (i < NN) ? deg[i] : 0;
        s += v[j];
    }
    part[t] = s;
    __syncthreads();
    for (int off = 1; off < 256; off <<= 1) {
        int x = (t >= off) ? part[t - off] : 0;
        __syncthreads();
        part[t] += x;
        __syncthreads();
    }
    int run = bbase + part[t] - s;
#pragma unroll
    for (int j = 0; j < 4; j++) {
        int i = base + j;
        if (i < NN) { rowptr[i] = run; cursor[i] = run; }
        run += v[j];
    }
    if (b == SCAN_B - 1 && t == 255) rowptr[NN] = NEDGE;
}

// ---- counting-sort scatter: order = node ids grouped by degree (load balance) ----
__global__ void k_dsort(const int* __restrict__ deg, int* __restrict__ dcur,
                        int* __restrict__ order) {
    __shared__ int lh[64], lbase[64];
    int t = threadIdx.x;
    if (t < 64) lh[t] = 0;
    __syncthreads();
    int i = blockIdx.x * 256 + t;
    int d = -1, lpos = 0;
    if (i < NN) {
        d = deg[i]; if (d > 63) d = 63;
        lpos = atomicAdd(&lh[d], 1);
    }
    __syncthreads();
    if (t < 64 && lh[t]) lbase[t] = atomicAdd(&dcur[t], lh[t]);
    __syncthreads();
    if (i < NN) order[lbase[d] + lpos] = i;
}

// packed fill: ONE 4B store per edge — (bf16 weight << 16) | src (src < 65536)
__global__ void k_fill(const int* __restrict__ ei, const void* __restrict__ ew,
                       const int* __restrict__ flags,
                       int* __restrict__ cursor, unsigned int* __restrict__ epk) {
    int e = (blockIdx.x * 256 + threadIdx.x) * 2;
    if (e >= NEDGE) return;
    int is64 = flags[0];
    int f32 = flags[1];
    int d0, s0, d1 = 0, s1 = 0;
    int has1 = (e + 1 < NEDGE);
    if (is64) {
        d0 = ei[2 * (NEDGE + e)];
        s0 = ei[2 * e];
        if (has1) { d1 = ei[2 * (NEDGE + e) + 2]; s1 = ei[2 * e + 2]; }
    } else {
        d0 = ei[NEDGE + e];
        s0 = ei[e];
        if (has1) { d1 = ei[NEDGE + e + 1]; s1 = ei[e + 1]; }
    }
    int p0 = atomicAdd(&cursor[d0], 1);
    int p1 = has1 ? atomicAdd(&cursor[d1], 1) : 0;
    unsigned int w0 = f2bf(ldf(ew, f32, e));
    epk[p0] = (w0 << 16) | (unsigned int)s0;
    if (has1) {
        unsigned int w1 = f2bf(ldf(ew, f32, e + 1));
        epk[p1] = (w1 << 16) | (unsigned int)s1;
    }
}

// ---- fused aggregate + residual RMW + next-block LN+ReLU ----
// nodes assigned via degree-sorted `order` so each wave's 4 nodes have ~equal degree.
__global__ __launch_bounds__(256) void k_aggln(
    const int* __restrict__ rowptr, const unsigned int* __restrict__ epk,
    const unsigned short* __restrict__ z,
    const float* __restrict__ cb,
    const int* __restrict__ order,
    unsigned short* __restrict__ h, int out_half,
    const float* __restrict__ ga, const float* __restrict__ be,
    unsigned short* __restrict__ amat,
    unsigned short* __restrict__ famat,
    int is_last)
{
    int slot = blockIdx.x * 16 + (threadIdx.x >> 4);
    int node = order[slot];
    int c8 = (threadIdx.x & 15) << 3;   // 8 channels/thread
    int beg = rowptr[node], end = rowptr[node + 1];
    unsigned short* hp = h + (long long)node * HIDC + out_half * GCH + c8;
    u16x8 hv = *(u16x8*)hp;             // residual xs[g], issued before gather
    const unsigned short* zb = z + c8;
    float acc[8];
#pragma unroll
    for (int j = 0; j < 8; j++) acc[j] = 0.f;

    int e = beg;
    for (; e + 7 < end; e += 8) {
        unsigned int pe[8];
        u16x8 v[8];
#pragma unroll
        for (int i = 0; i < 8; i++) pe[i] = epk[e + i];
#pragma unroll
        for (int i = 0; i < 8; i++)
            v[i] = *(const u16x8*)(zb + (long long)(pe[i] & 0xFFFFu) * GCH);
#pragma unroll
        for (int i = 0; i < 8; i++) {
            float w = bf2f((unsigned short)(pe[i] >> 16));
#pragma unroll
            for (int j = 0; j < 8; j++) acc[j] += w * bf2f(v[i][j]);
        }
    }
    if (e + 3 < end) {
        unsigned int pe[4];
        u16x8 v[4];
#pragma unroll
        for (int i = 0; i < 4; i++) pe[i] = epk[e + i];
#pragma unroll
        for (int i = 0; i < 4; i++)
            v[i] = *(const u16x8*)(zb + (long long)(pe[i] & 0xFFFFu) * GCH);
#pragma unroll
        for (int i = 0; i < 4; i++) {
            float w = bf2f((unsigned short)(pe[i] >> 16));
#pragma unroll
            for (int j = 0; j < 8; j++) acc[j] += w * bf2f(v[i][j]);
        }
        e += 4;
    }
    for (; e < end; e++) {
        unsigned int pe = epk[e];
        float w0 = bf2f((unsigned short)(pe >> 16));
        u16x8 v = *(const u16x8*)(zb + (long long)(pe & 0xFFFFu) * GCH);
#pragma unroll
        for (int j = 0; j < 8; j++) acc[j] += w0 * bf2f(v[j]);
    }

    // residual add + bf16 round (matches prior numerics: LN reads rounded values)
    float y[8]; float sum = 0.f, sq = 0.f;
#pragma unroll
    for (int j = 0; j < 8; j++) {
        float yy = bf2f(hv[j]) + acc[j] + cb[c8 + j];
        unsigned short r = f2bf(yy);
        hv[j] = r;
        y[j] = bf2f(r);
        sum += y[j]; sq += y[j] * y[j];
    }
    *(u16x8*)hp = hv;

    float oy[8];
    if (is_last) {                       // final LN is over all 256 channels
        u16x8 ov = *(const u16x8*)(h + (long long)node * HIDC + (out_half ^ 1) * GCH + c8);
#pragma unroll
        for (int j = 0; j < 8; j++) {
            oy[j] = bf2f(ov[j]);
            sum += oy[j]; sq += oy[j] * oy[j];
        }
    }
    sum += __shfl_xor(sum, 1, 64); sum += __shfl_xor(sum, 2, 64);
    sum += __shfl_xor(sum, 4, 64); sum += __shfl_xor(sum, 8, 64);
    sq  += __shfl_xor(sq, 1, 64);  sq  += __shfl_xor(sq, 2, 64);
    sq  += __shfl_xor(sq, 4, 64);  sq  += __shfl_xor(sq, 8, 64);
    float inv = is_last ? (1.0f / HIDC) : (1.0f / GCH);
    float mu = sum * inv;
    float var = sq * inv - mu * mu;
    float rs = rsqrtf(var + EPSV);

    if (!is_last) {
        u16x8 o;
#pragma unroll
        for (int j = 0; j < 8; j++) {
            float val = (y[j] - mu) * rs * ga[c8 + j] + be[c8 + j];
            if (val < 0.f) val = 0.f;
            o[j] = f2bf(val);
        }
        *(u16x8*)(amat + (long long)node * GCH + c8) = o;
    } else {
        u16x8 o;
        int cn = out_half * GCH + c8;
#pragma unroll
        for (int j = 0; j < 8; j++) {
            float val = (y[j] - mu) * rs * ga[cn + j] + be[cn + j];
            if (val < 0.f) val = 0.f;
            o[j] = f2bf(val);
        }
        *(u16x8*)(famat + (long long)node * HIDC + cn) = o;
        int co = (out_half ^ 1) * GCH + c8;
#pragma unroll
        for (int j = 0; j < 8; j++) {
            float val = (oy[j] - mu) * rs * ga[co + j] + be[co + j];
            if (val < 0.f) val = 0.f;
            o[j] = f2bf(val);
        }
        *(u16x8*)(famat + (long long)node * HIDC + co) = o;
    }
}

// ---- final: out = famat @ W2 + b2 (famat pre-normalized, LDS-staged) ----
__global__ __launch_bounds__(256) void k_final(
    const unsigned short* __restrict__ famat,
    const unsigned short* __restrict__ w2t,
    const float* __restrict__ b2f,
    const int* __restrict__ flags,
    void* __restrict__ out)
{
    __shared__ __align__(16) unsigned short a_tile[64 * 256];
    int t = threadIdx.x;
    int r0 = blockIdx.x * 64;
    const char* gb = (const char*)famat + (long long)r0 * 512;
#pragma unroll
    for (int i = 0; i < 8; i++) {
        int lb = (i * 256 + t) * 16;
        int row = lb >> 9;
        int c = lb & 511;
        gload_lds16(gb + (long long)row * 512 + (c ^ ((row & 7) << 4)),
                    (char*)a_tile + lb);
    }
    __syncthreads();

    int w = t >> 6, lane = t & 63;
    int quad = lane >> 4, ln = lane & 15;
    const f32x4 zf = {0.f, 0.f, 0.f, 0.f};
    f32x4 acc[3];
#pragma unroll
    for (int j = 0; j < 3; j++) acc[j] = zf;
#pragma unroll
    for (int kk = 0; kk < 8; kk++) {
        int kb = kk * 64 + quad * 16;
        int ko = kk * 32 + quad * 8;
        int row = w * 16 + ln;
        bf16x8 a = *(const bf16x8*)((const char*)a_tile + row * 512 + (kb ^ ((row & 7) << 4)));
#pragma unroll
        for (int nf = 0; nf < 3; nf++) {
            bf16x8 b = ld8(w2t + (long long)(nf * 16 + ln) * HIDC + ko);
            acc[nf] = __builtin_amdgcn_mfma_f32_16x16x32_bf16(a, b, acc[nf], 0, 0, 0);
        }
    }
    int f32o = flags[1];
#pragma unroll
    for (int nf = 0; nf < 3; nf++) {
        int col = nf * 16 + ln;
        if (col >= OUTC) continue;
        float bias = b2f[col];
#pragma unroll
        for (int r4 = 0; r4 < 4; r4++) {
            int row2 = r0 + w * 16 + quad * 4 + r4;
            if (row2 < NN) {
                float val = acc[nf][r4] + bias;
                long long o = (long long)row2 * OUTC + col;
                if (f32o) ((float*)out)[o] = val;
                else      ((unsigned short*)out)[o] = f2bf(val);
            }
        }
    }
}

extern "C" void kernel_launch(void* const* d_in, const int* in_sizes, int n_in,
                              void* d_out, int out_size, void* d_ws, size_t ws_size,
                              hipStream_t stream)
{
    const void* x       = d_in[0];
    const int*  ei      = (const int*)d_in[1];
    const void* ew      = d_in[2];
    const void* lin1_w  = d_in[3];
    const void* lin1_b  = d_in[4];
    const void* lin2_w  = d_in[5];
    const void* lin2_b  = d_in[6];
    const void* norm_g  = d_in[7];
    const void* norm_b  = d_in[8];
    const void* conv_w  = d_in[9];
    const void* conv_b  = d_in[10];
    const void* fnorm_g = d_in[11];
    const void* fnorm_b = d_in[12];

    char* ws = (char*)d_ws;
    size_t off = 0;
    auto alloc = [&](size_t bytes) { void* p = (void*)(ws + off); off += (bytes + 255) & ~255ull; return p; };

    unsigned short* h      = (unsigned short*)alloc((size_t)NN * HIDC * 2);
    unsigned short* z      = (unsigned short*)alloc((size_t)NN * GCH * 2);
    unsigned short* amat   = (unsigned short*)alloc((size_t)(NN + 128) * GCH * 2);  // +pad: tile OOB reads
    unsigned short* famat  = (unsigned short*)alloc((size_t)(NN + 64) * HIDC * 2);  // +pad
    unsigned short* xb     = (unsigned short*)alloc((size_t)NN * INC * 2);
    unsigned short* w1t    = (unsigned short*)alloc((size_t)CVT_W1 * 2);
    unsigned short* cwt    = (unsigned short*)alloc((size_t)CVT_CW * 2);
    unsigned short* w2t    = (unsigned short*)alloc((size_t)CVT_W2 * 2);
    float*          b1f    = (float*)alloc(256 * 4);
    float*          ngf    = (float*)alloc(1024 * 4);
    float*          nbf    = (float*)alloc(1024 * 4);
    float*          cbf    = (float*)alloc(1024 * 4);
    float*          fgf    = (float*)alloc(256 * 4);
    float*          fbf    = (float*)alloc(256 * 4);
    float*          b2f    = (float*)alloc(48 * 4);
    int*            deg    = (int*)alloc((size_t)NN * 4);
    int*            rowptr = (int*)alloc(((size_t)NN + 1) * 4);
    int*            cursor = (int*)alloc((size_t)NN * 4);
    int*            order  = (int*)alloc((size_t)NN * 4);
    unsigned int*   epk    = (unsigned int*)alloc((size_t)NEDGE * 4);
    int*            flags  = (int*)alloc(256);
    int*            bsum   = (int*)alloc(SCAN_B * 4);
    int*            dhist  = (int*)alloc(64 * 4);
    int*            dcur   = (int*)alloc(64 * 4);

    if (ws_size < off || n_in < 13) {
        float mv = 100.0f + (float)(ws_size >> 20) + ((n_in < 13) ? 10000.0f : 0.0f);
        k_marker<<<(out_size + 255) / 256, 256, 0, stream>>>(d_out, mv, out_size);
        return;
    }

    k_detect<<<196, 256, 0, stream>>>(ei, (const unsigned short*)x, flags, deg, dhist);
    k_convert<<<CVT_TOT / 256 + 1, 256, 0, stream>>>(x, lin1_w, conv_w, lin2_w,
                                                     lin1_b, norm_g, norm_b, conv_b,
                                                     fnorm_g, fnorm_b, lin2_b, flags,
                                                     xb, w1t, cwt, w2t,
                                                     b1f, ngf, nbf, cbf, fgf, fbf, b2f);
    k_lin1<<<782, 256, 0, stream>>>((const unsigned short*)x, xb, w1t, b1f, flags, h);
    k_ln_amat<<<NN / 16, 256, 0, stream>>>(h, ngf, nbf, amat);

    k_count<<<(NEDGE / 2 + 255) / 256, 256, 0, stream>>>(ei, flags, deg);
    k_scan_a<<<SCAN_B, 256, 0, stream>>>(deg, bsum, dhist);
    k_scan_c<<<SCAN_B, 256, 0, stream>>>(deg, bsum, rowptr, cursor, dhist, dcur);
    k_dsort<<<196, 256, 0, stream>>>(deg, dcur, order);
    k_fill<<<(NEDGE / 2 + 255) / 256, 256, 0, stream>>>(ei, ew, flags, cursor, epk);

    const int AGG_B = NN / 16;   // 3125
    for (int lg = 0; lg < NL * NG; lg++) {
        int is_last = (lg == NL * NG - 1);
        k_gemm<<<391, 256, 0, stream>>>(amat, cwt + (size_t)lg * GCH * GCH, z);
        k_aggln<<<AGG_B, 256, 0, stream>>>(rowptr, epk, z, cbf + lg * GCH, order,
                                           h, lg & 1,
                                           is_last ? fgf : (ngf + (lg + 1) * GCH),
                                           is_last ? fbf : (nbf + (lg + 1) * GCH),
                                           amat, famat, is_last);
    }
    k_final<<<782, 256, 0, stream>>>(famat, w2t, b2f, flags, d_out);
}